// Round 1
// baseline (666.795 us; speedup 1.0000x reference)
//
#include <hip/hip_runtime.h>
#include <math.h>

#define B_   256
#define N_   129
#define C_   768
#define C4_  192
#define HD_  256
#define NSP_ 38
#define NTOK_ (B_*N_)   // 33024

// ---------- A: cls_n = cls / max(||cls||, eps) ----------
__global__ __launch_bounds__(256) void k_clsnorm(const float* __restrict__ F,
                                                 float* __restrict__ cls_n) {
  const int b = blockIdx.x;
  const int t = threadIdx.x;
  const float* row = F + (size_t)b * (N_ * C_);
  float s = 0.f;
  for (int k = t; k < C_; k += 256) { float v = row[k]; s += v * v; }
  for (int off = 32; off > 0; off >>= 1) s += __shfl_down(s, off);
  __shared__ float red[4];
  __shared__ float inv_s;
  if ((t & 63) == 0) red[t >> 6] = s;
  __syncthreads();
  if (t == 0) {
    float tot = red[0] + red[1] + red[2] + red[3];
    float nrm = fmaxf(sqrtf(tot), 1e-12f);
    inv_s = 1.f / nrm;
  }
  __syncthreads();
  const float inv = inv_s;
  for (int k = t; k < C_; k += 256) cls_n[(size_t)b * C_ + k] = row[k] * inv;
}

// ---------- B: sim = cls_n@cls_n^T, mask same-label, top-4, keep ranks 2,3 ----------
__global__ __launch_bounds__(256) void k_sim_top4(const float* __restrict__ cls_n,
                                                  const int* __restrict__ labels,
                                                  int* __restrict__ swap_idx) {
  const int b = blockIdx.x;
  const int t = threadIdx.x;  // one thread per candidate j
  __shared__ float a[C_];
  for (int k = t; k < C_; k += 256) a[k] = cls_n[(size_t)b * C_ + k];
  __syncthreads();
  const int lb = labels[b];
  float s;
  if (labels[t] == lb) {
    s = -INFINITY;
  } else {
    const float* rowj = cls_n + (size_t)t * C_;
    float acc = 0.f;
    for (int k = 0; k < C_; ++k) acc = fmaf(a[k], rowj[k], acc);
    s = acc;
  }
  __shared__ float svals[B_];
  __shared__ float wv[4];
  __shared__ int   wi[4];
  __shared__ int   top4[4];
  svals[t] = s;
  for (int it = 0; it < 4; ++it) {
    __syncthreads();
    float v = svals[t]; int idx = t;
    for (int off = 32; off > 0; off >>= 1) {
      float ov = __shfl_down(v, off);
      int   oi = __shfl_down(idx, off);
      if (ov > v || (ov == v && oi < idx)) { v = ov; idx = oi; }
    }
    if ((t & 63) == 0) { wv[t >> 6] = v; wi[t >> 6] = idx; }
    __syncthreads();
    if (t == 0) {
      float bv = wv[0]; int bi = wi[0];
      for (int w = 1; w < 4; ++w)
        if (wv[w] > bv || (wv[w] == bv && wi[w] < bi)) { bv = wv[w]; bi = wi[w]; }
      top4[it] = bi;
      svals[bi] = -INFINITY;
    }
  }
  __syncthreads();
  if (t == 0) { swap_idx[b * 2 + 0] = top4[2]; swap_idx[b * 2 + 1] = top4[3]; }
}

// ---------- C: M = W2 @ V1  (192x256, K=768) ----------
__global__ __launch_bounds__(256) void k_M(const float* __restrict__ W2,
                                           const float* __restrict__ V1,
                                           float* __restrict__ Mm) {
  const int i = blockIdx.x;   // 192
  const int j = threadIdx.x;  // 256
  const float* w2r = W2 + (size_t)i * C_;
  float acc = 0.f;
  for (int k = 0; k < C_; ++k) acc = fmaf(w2r[k], V1[(size_t)k * HD_ + j], acc);
  Mm[(size_t)i * HD_ + j] = acc;
}

// ---------- C2: d = b2 @ V1 + c1 ----------
__global__ __launch_bounds__(256) void k_d(const float* __restrict__ b2,
                                           const float* __restrict__ V1,
                                           const float* __restrict__ c1,
                                           float* __restrict__ dv) {
  const int j = threadIdx.x;
  float acc = c1[j];
  for (int k = 0; k < C_; ++k) acc = fmaf(b2[k], V1[(size_t)k * HD_ + j], acc);
  dv[j] = acc;
}

// ---------- D1: H = relu(F @ W1 + b1)   (33024 x 192, K=768) ----------
// block: 192 threads, tile 64 rows x 192 cols, thread tile 8x8
__global__ __launch_bounds__(192) void k_mlp1(const float* __restrict__ F,
                                              const float* __restrict__ W1,
                                              const float* __restrict__ b1,
                                              float* __restrict__ H) {
  __shared__ float Fs[32][68];     // [k][row], padded for b128 reads
  __shared__ float Ws[32][C4_];    // [k][col]
  const int t = threadIdx.x;
  const int row0 = blockIdx.x * 64;
  const int ct = t % 24;           // 24 col-threads * 8 cols
  const int rt = t / 24;           // 8 row-threads  * 8 rows
  float acc[8][8];
#pragma unroll
  for (int i = 0; i < 8; ++i)
#pragma unroll
    for (int j = 0; j < 8; ++j) acc[i][j] = 0.f;

  for (int kt = 0; kt < C_ / 32; ++kt) {
    const int k0 = kt * 32;
    for (int idx = t; idx < 64 * 32; idx += 192) {
      const int r = idx >> 5, kk = idx & 31;
      Fs[kk][r] = F[(size_t)(row0 + r) * C_ + k0 + kk];
    }
    for (int idx = t; idx < 32 * C4_; idx += 192) {
      const int kk = idx / C4_, j = idx % C4_;
      Ws[kk][j] = W1[(size_t)(k0 + kk) * C4_ + j];
    }
    __syncthreads();
#pragma unroll 4
    for (int kk = 0; kk < 32; ++kk) {
      float fv[8], wvv[8];
#pragma unroll
      for (int i = 0; i < 8; ++i) fv[i] = Fs[kk][rt * 8 + i];
#pragma unroll
      for (int j = 0; j < 8; ++j) wvv[j] = Ws[kk][ct * 8 + j];
#pragma unroll
      for (int i = 0; i < 8; ++i)
#pragma unroll
        for (int j = 0; j < 8; ++j) acc[i][j] = fmaf(fv[i], wvv[j], acc[i][j]);
    }
    __syncthreads();
  }
#pragma unroll
  for (int i = 0; i < 8; ++i) {
    const int r = row0 + rt * 8 + i;
#pragma unroll
    for (int j = 0; j < 8; ++j) {
      const int col = ct * 8 + j;
      H[(size_t)r * C4_ + col] = fmaxf(acc[i][j] + b1[col], 0.f);
    }
  }
}

// ---------- D2: imp = relu(H @ M + d) @ V2 + c2   (33024, K=192 then 256) ----------
// block: 256 threads, tile 64 rows x 256 cols, thread tile 8x8, shfl-reduce over 32 col-threads
__global__ __launch_bounds__(256) void k_mlp2(const float* __restrict__ H,
                                              const float* __restrict__ Mm,
                                              const float* __restrict__ dv,
                                              const float* __restrict__ V2,
                                              const float* __restrict__ c2,
                                              float* __restrict__ imp) {
  __shared__ float Hs[32][68];
  __shared__ float Ms[32][HD_];
  const int t = threadIdx.x;
  const int row0 = blockIdx.x * 64;
  const int ct = t & 31;   // 32 col-threads * 8 cols
  const int rt = t >> 5;   // 8 row-threads  * 8 rows
  float acc[8][8];
#pragma unroll
  for (int i = 0; i < 8; ++i)
#pragma unroll
    for (int j = 0; j < 8; ++j) acc[i][j] = 0.f;

  for (int kt = 0; kt < C4_ / 32; ++kt) {
    const int k0 = kt * 32;
    for (int idx = t; idx < 64 * 32; idx += 256) {
      const int r = idx >> 5, kk = idx & 31;
      Hs[kk][r] = H[(size_t)(row0 + r) * C4_ + k0 + kk];
    }
    for (int idx = t; idx < 32 * HD_; idx += 256) {
      const int kk = idx >> 8, j = idx & 255;
      Ms[kk][j] = Mm[(size_t)(k0 + kk) * HD_ + j];
    }
    __syncthreads();
#pragma unroll 4
    for (int kk = 0; kk < 32; ++kk) {
      float hv[8], mv[8];
#pragma unroll
      for (int i = 0; i < 8; ++i) hv[i] = Hs[kk][rt * 8 + i];
#pragma unroll
      for (int j = 0; j < 8; ++j) mv[j] = Ms[kk][ct * 8 + j];
#pragma unroll
      for (int i = 0; i < 8; ++i)
#pragma unroll
        for (int j = 0; j < 8; ++j) acc[i][j] = fmaf(hv[i], mv[j], acc[i][j]);
    }
    __syncthreads();
  }
  float dvv[8], v2v[8];
#pragma unroll
  for (int j = 0; j < 8; ++j) { dvv[j] = dv[ct * 8 + j]; v2v[j] = V2[ct * 8 + j]; }
  const float c2v = c2[0];
#pragma unroll
  for (int i = 0; i < 8; ++i) {
    float s = 0.f;
#pragma unroll
    for (int j = 0; j < 8; ++j) {
      float g = fmaxf(acc[i][j] + dvv[j], 0.f);
      s = fmaf(g, v2v[j], s);
    }
#pragma unroll
    for (int off = 1; off < 32; off <<= 1) s += __shfl_xor(s, off);
    if (ct == 0) imp[(size_t)(row0 + rt * 8 + i)] = s + c2v;
  }
}

// ---------- E: per-b top-38 of imp (desc, low-index tie-break) -> swap_map ----------
// swap_map[b][adj] = rank it (last-wins for the only possible 0/1 collision), -1 = no swap
__global__ __launch_bounds__(64) void k_top38(const float* __restrict__ imp,
                                              int* __restrict__ swap_map) {
  const int b = blockIdx.x;
  const int t = threadIdx.x;
  __shared__ float vals[N_];
  __shared__ int top[NSP_];
  for (int i = t; i < N_; i += 64) vals[i] = imp[(size_t)b * N_ + i];
  for (int i = t; i < N_ - 1; i += 64) swap_map[b * (N_ - 1) + i] = -1;
  __syncthreads();
  for (int it = 0; it < NSP_; ++it) {
    float v = -INFINITY; int idx = N_;
    for (int i = t; i < N_; i += 64) {
      float x = vals[i];
      if (x > v || (x == v && i < idx)) { v = x; idx = i; }
    }
    for (int off = 32; off > 0; off >>= 1) {
      float ov = __shfl_xor(v, off);
      int   oi = __shfl_xor(idx, off);
      if (ov > v || (ov == v && oi < idx)) { v = ov; idx = oi; }
    }
    if (t == 0) { top[it] = idx; vals[idx] = -INFINITY; }
    __syncthreads();
  }
  if (t == 0) {
    for (int it = 0; it < NSP_; ++it) {
      const int idx = top[it];
      const int adj = idx > 0 ? idx - 1 : 0;
      swap_map[b * (N_ - 1) + adj] = it;   // serial, rank order => last wins
    }
  }
}

// ---------- F: out = 0.7*features + 0.3*swapped ----------
__global__ __launch_bounds__(192) void k_blend(const float* __restrict__ F,
                                               const float* __restrict__ cls_n,
                                               const int* __restrict__ swap_map,
                                               const int* __restrict__ swap_choice,
                                               const int* __restrict__ swap_idx,
                                               float* __restrict__ out) {
  const int token = blockIdx.x;
  const int b = token / N_;
  const int n = token - b * N_;
  const int t = threadIdx.x;  // 192 threads * float4 = 768
  const float4* fin = (const float4*)(F + (size_t)token * C_);
  float4 x = fin[t];
  float4 y = x;
  if (n > 0) {
    const int it = swap_map[b * (N_ - 1) + n - 1];
    if (it >= 0) {
      const int choice = swap_choice[b * NSP_ + it];
      const int sb = swap_idx[b * 2 + choice];
      y = ((const float4*)(cls_n + (size_t)sb * C_))[t];
    }
  }
  float4 o;
  o.x = 0.7f * x.x + 0.3f * y.x;
  o.y = 0.7f * x.y + 0.3f * y.y;
  o.z = 0.7f * x.z + 0.3f * y.z;
  o.w = 0.7f * x.w + 0.3f * y.w;
  ((float4*)(out + (size_t)token * C_))[t] = o;
}

extern "C" void kernel_launch(void* const* d_in, const int* in_sizes, int n_in,
                              void* d_out, int out_size, void* d_ws, size_t ws_size,
                              hipStream_t stream) {
  const float* F   = (const float*)d_in[0];
  const float* W1  = (const float*)d_in[1];
  const float* b1  = (const float*)d_in[2];
  const float* W2  = (const float*)d_in[3];
  const float* b2  = (const float*)d_in[4];
  const float* V1  = (const float*)d_in[5];
  const float* c1  = (const float*)d_in[6];
  const float* V2  = (const float*)d_in[7];
  const float* c2  = (const float*)d_in[8];
  const int* labels      = (const int*)d_in[9];
  const int* swap_choice = (const int*)d_in[10];
  float* out = (float*)d_out;

  char* ws = (char*)d_ws;
  size_t off = 0;
  auto alloc = [&](size_t bytes) -> void* {
    void* p = ws + off;
    off = (off + bytes + 255) & ~(size_t)255;
    return p;
  };
  float* cls_n   = (float*)alloc((size_t)B_ * C_ * 4);
  float* Hbuf    = (float*)alloc((size_t)NTOK_ * C4_ * 4);
  float* Mm      = (float*)alloc((size_t)C4_ * HD_ * 4);
  float* dv      = (float*)alloc((size_t)HD_ * 4);
  float* imp     = (float*)alloc((size_t)NTOK_ * 4);
  int*   swapIdx = (int*)alloc((size_t)B_ * 2 * 4);
  int*   swapMap = (int*)alloc((size_t)B_ * (N_ - 1) * 4);
  if (off > ws_size) return;  // workspace too small -> fail loudly

  k_clsnorm<<<B_, 256, 0, stream>>>(F, cls_n);
  k_sim_top4<<<B_, 256, 0, stream>>>(cls_n, labels, swapIdx);
  k_M<<<C4_, HD_, 0, stream>>>(W2, V1, Mm);
  k_d<<<1, HD_, 0, stream>>>(b2, V1, c1, dv);
  k_mlp1<<<NTOK_ / 64, 192, 0, stream>>>(F, W1, b1, Hbuf);
  k_mlp2<<<NTOK_ / 64, 256, 0, stream>>>(Hbuf, Mm, dv, V2, c2, imp);
  k_top38<<<B_, 64, 0, stream>>>(imp, swapMap);
  k_blend<<<NTOK_, 192, 0, stream>>>(F, cls_n, swapMap, swap_choice, swapIdx, out);
}

// Round 6
// 527.177 us; speedup vs baseline: 1.2648x; 1.2648x over previous
//
#include <hip/hip_runtime.h>
#include <math.h>

#define B_   256
#define N_   129
#define C_   768
#define C4_  192
#define HD_  256
#define NSP_ 38
#define NTOK_ (B_*N_)   // 33024

typedef __attribute__((ext_vector_type(8))) short bf16x8;
typedef __attribute__((ext_vector_type(4))) float f32x4;

static __device__ __forceinline__ unsigned short f2bf(float x) {
  unsigned u = __float_as_uint(x);
  u += 0x7FFFu + ((u >> 16) & 1u);
  return (unsigned short)(u >> 16);
}
static __device__ __forceinline__ float bf2f(unsigned short h) {
  return __uint_as_float(((unsigned)h) << 16);
}
// 3-way split: x ~= h + m + l, residual ~2^-27 |x|
static __device__ __forceinline__ void split3(float x, unsigned short& h,
                                              unsigned short& m, unsigned short& l) {
  h = f2bf(x);
  float r1 = x - bf2f(h);
  m = f2bf(r1);
  float r2 = r1 - bf2f(m);
  l = f2bf(r2);
}

// ---------- A: cls_n = cls / max(||cls||, eps); also transposed copy ----------
__global__ __launch_bounds__(256) void k_clsnorm(const float* __restrict__ F,
                                                 float* __restrict__ cls_n,
                                                 float* __restrict__ cls_nT) {
  const int b = blockIdx.x;
  const int t = threadIdx.x;
  const float* row = F + (size_t)b * (N_ * C_);
  float s = 0.f;
  for (int k = t; k < C_; k += 256) { float v = row[k]; s += v * v; }
  for (int off = 32; off > 0; off >>= 1) s += __shfl_down(s, off);
  __shared__ float red[4];
  __shared__ float inv_s;
  if ((t & 63) == 0) red[t >> 6] = s;
  __syncthreads();
  if (t == 0) {
    float tot = red[0] + red[1] + red[2] + red[3];
    inv_s = 1.f / fmaxf(sqrtf(tot), 1e-12f);
  }
  __syncthreads();
  const float inv = inv_s;
  for (int k = t; k < C_; k += 256) {
    float v = row[k] * inv;
    cls_n[(size_t)b * C_ + k] = v;
    cls_nT[(size_t)k * B_ + b] = v;
  }
}

// ---------- B: sim, mask same-label, top-4, keep ranks 2,3 ----------
__global__ __launch_bounds__(256) void k_sim_top4(const float* __restrict__ cls_nT,
                                                  const int* __restrict__ labels,
                                                  int* __restrict__ swap_idx) {
  const int b = blockIdx.x;
  const int t = threadIdx.x;  // candidate j
  __shared__ float a[C_];
  for (int k = t; k < C_; k += 256) a[k] = cls_nT[(size_t)k * B_ + b];
  __syncthreads();
  const int lb = labels[b];
  float s;
  if (labels[t] == lb) {
    s = -INFINITY;
  } else {
    float acc = 0.f;
#pragma unroll 4
    for (int k = 0; k < C_; ++k) acc = fmaf(a[k], cls_nT[(size_t)k * B_ + t], acc);
    s = acc;
  }
  __shared__ float svals[B_];
  __shared__ float wv[4];
  __shared__ int   wi[4];
  __shared__ int   top4[4];
  svals[t] = s;
  for (int it = 0; it < 4; ++it) {
    __syncthreads();
    float v = svals[t]; int idx = t;
    for (int off = 32; off > 0; off >>= 1) {
      float ov = __shfl_down(v, off);
      int   oi = __shfl_down(idx, off);
      if (ov > v || (ov == v && oi < idx)) { v = ov; idx = oi; }
    }
    if ((t & 63) == 0) { wv[t >> 6] = v; wi[t >> 6] = idx; }
    __syncthreads();
    if (t == 0) {
      float bv = wv[0]; int bi = wi[0];
      for (int w = 1; w < 4; ++w)
        if (wv[w] > bv || (wv[w] == bv && wi[w] < bi)) { bv = wv[w]; bi = wi[w]; }
      top4[it] = bi;
      svals[bi] = -INFINITY;
    }
  }
  __syncthreads();
  if (t == 0) { swap_idx[b * 2 + 0] = top4[2]; swap_idx[b * 2 + 1] = top4[3]; }
}

// ---------- W1 -> fragment-linear 3-way split-bf16 ----------
__global__ __launch_bounds__(192) void k_w1frag(const float* __restrict__ W1,
                                                unsigned short* __restrict__ W1h,
                                                unsigned short* __restrict__ W1m,
                                                unsigned short* __restrict__ W1l) {
  const int k = blockIdx.x;   // 0..767
  const int n = threadIdx.x;  // 0..191
  const float x = W1[(size_t)k * C4_ + n];
  const int ks = k >> 5, nt = n >> 4;
  const int ll = ((k >> 3) & 3) * 16 + (n & 15);
  const int jj = k & 7;
  const size_t flat = (((size_t)nt * 24 + ks) * 64 + ll) * 8 + jj;
  unsigned short h, m, l;
  split3(x, h, m, l);
  W1h[flat] = h; W1m[flat] = m; W1l[flat] = l;
}

// ---------- M = W2 @ V1, plain fp32 (r1-validated) ----------
__global__ __launch_bounds__(256) void k_M(const float* __restrict__ W2,
                                           const float* __restrict__ V1,
                                           float* __restrict__ Mm) {
  const int i = blockIdx.x;   // 192
  const int j = threadIdx.x;  // 256
  const float* w2r = W2 + (size_t)i * C_;
  float acc = 0.f;
#pragma unroll 4
  for (int k = 0; k < C_; ++k) acc = fmaf(w2r[k], V1[(size_t)k * HD_ + j], acc);
  Mm[(size_t)i * HD_ + j] = acc;
}

// ---------- d = b2 @ V1 + c1 ----------
__global__ __launch_bounds__(256) void k_d(const float* __restrict__ b2,
                                           const float* __restrict__ V1,
                                           const float* __restrict__ c1,
                                           float* __restrict__ dv) {
  const int j = threadIdx.x;
  float acc = c1[j];
  for (int k = 0; k < C_; ++k) acc = fmaf(b2[k], V1[(size_t)k * HD_ + j], acc);
  dv[j] = acc;
}

#define MFMA6(ACC, AH, AM, AL, BH, BM, BL)                                   \
  ACC = __builtin_amdgcn_mfma_f32_16x16x32_bf16(AH, BH, ACC, 0, 0, 0);       \
  ACC = __builtin_amdgcn_mfma_f32_16x16x32_bf16(AH, BM, ACC, 0, 0, 0);       \
  ACC = __builtin_amdgcn_mfma_f32_16x16x32_bf16(AM, BH, ACC, 0, 0, 0);       \
  ACC = __builtin_amdgcn_mfma_f32_16x16x32_bf16(AM, BM, ACC, 0, 0, 0);       \
  ACC = __builtin_amdgcn_mfma_f32_16x16x32_bf16(AH, BL, ACC, 0, 0, 0);       \
  ACC = __builtin_amdgcn_mfma_f32_16x16x32_bf16(AL, BH, ACC, 0, 0, 0);

// ---------- hybrid fused: stage1 = split-bf16 MFMA (F@W1), stage2/3 = fp32 VALU ----------
// block = 256 thr (4 waves), 64 token rows. LDS overlay: A-planes then fp32 H.
__global__ __launch_bounds__(256) void k_fused2(const float* __restrict__ F,
                                                const unsigned short* __restrict__ W1h,
                                                const unsigned short* __restrict__ W1m,
                                                const unsigned short* __restrict__ W1l,
                                                const float* __restrict__ b1,
                                                const float* __restrict__ Mm,
                                                const float* __restrict__ dv,
                                                const float* __restrict__ V2,
                                                const float* __restrict__ c2,
                                                float* __restrict__ imp) {
  __shared__ __align__(16) char smem[64 * 200 * 4];     // 51.2 KB
  unsigned short (*Ah)[40] = (unsigned short(*)[40])(smem);
  unsigned short (*Am)[40] = (unsigned short(*)[40])(smem + 5120);
  unsigned short (*Al)[40] = (unsigned short(*)[40])(smem + 10240);
  float (*Hs)[200] = (float(*)[200])(smem);             // overlays A (safe: sync'd)

  const int t = threadIdx.x;
  const int w = t >> 6;
  const int l = t & 63;
  const int l15 = l & 15, l4 = l >> 4;
  const int row0 = blockIdx.x * 64;

  f32x4 acc[4][3];
#pragma unroll
  for (int i = 0; i < 4; ++i)
#pragma unroll
    for (int j = 0; j < 3; ++j) acc[i][j] = (f32x4){0.f, 0.f, 0.f, 0.f};

  // staging map: thread -> (row sr, k-octet sk)
  const int sr = t >> 2;
  const int sk = (t & 3) * 8;
  const float* fptr = F + (size_t)(row0 + sr) * C_ + sk;

  float4 p0 = *(const float4*)(fptr);
  float4 p1 = *(const float4*)(fptr + 4);

  for (int ks = 0; ks < 24; ++ks) {
    __syncthreads();   // previous compute done reading A planes
    {
      float xs[8] = {p0.x, p0.y, p0.z, p0.w, p1.x, p1.y, p1.z, p1.w};
      union { bf16x8 v; unsigned short s[8]; } hv, mv, lv;
#pragma unroll
      for (int j = 0; j < 8; ++j) {
        unsigned short h, m, lo;
        split3(xs[j], h, m, lo);
        hv.s[j] = (short)h; mv.s[j] = (short)m; lv.s[j] = (short)lo;
      }
      *(bf16x8*)&Ah[sr][sk] = hv.v;
      *(bf16x8*)&Am[sr][sk] = mv.v;
      *(bf16x8*)&Al[sr][sk] = lv.v;
    }
    if (ks + 1 < 24) {   // prefetch next k-slab
      const float* nf = fptr + (ks + 1) * 32;
      p0 = *(const float4*)(nf);
      p1 = *(const float4*)(nf + 4);
    }
    __syncthreads();     // tile ready

    bf16x8 afh[4], afm[4], afl[4];
#pragma unroll
    for (int rt = 0; rt < 4; ++rt) {
      afh[rt] = *(const bf16x8*)&Ah[16 * rt + l15][l4 * 8];
      afm[rt] = *(const bf16x8*)&Am[16 * rt + l15][l4 * 8];
      afl[rt] = *(const bf16x8*)&Al[16 * rt + l15][l4 * 8];
    }
#pragma unroll
    for (int ntl = 0; ntl < 3; ++ntl) {
      const int nt = 3 * w + ntl;
      const size_t boff = (((size_t)nt * 24 + ks) * 64 + l) * 8;
      const bf16x8 bh = *(const bf16x8*)(W1h + boff);
      const bf16x8 bm = *(const bf16x8*)(W1m + boff);
      const bf16x8 bl = *(const bf16x8*)(W1l + boff);
#pragma unroll
      for (int rt = 0; rt < 4; ++rt) {
        MFMA6(acc[rt][ntl], afh[rt], afm[rt], afl[rt], bh, bm, bl)
      }
    }
  }

  // epilogue stage1: H = relu(acc + b1) -> fp32 LDS (overlays dead A planes)
  float b1v[3];
#pragma unroll
  for (int ntl = 0; ntl < 3; ++ntl) b1v[ntl] = b1[16 * (3 * w + ntl) + l15];
  __syncthreads();   // all waves done reading A planes
#pragma unroll
  for (int rt = 0; rt < 4; ++rt)
#pragma unroll
    for (int ntl = 0; ntl < 3; ++ntl) {
      const int col = 16 * (3 * w + ntl) + l15;
#pragma unroll
      for (int r = 0; r < 4; ++r) {
        const int row = 16 * rt + l4 * 4 + r;
        Hs[row][col] = fmaxf(acc[rt][ntl][r] + b1v[ntl], 0.f);
      }
    }
  __syncthreads();

  // stage2: pre = H @ M in exact fp32 (r1 semantics), stage3 fused
  const int ct = t & 31;   // 32 col-threads * 8 cols = 256
  const int rt2 = t >> 5;  // 8 row-threads * 8 rows = 64
  float acc2[8][8];
#pragma unroll
  for (int i = 0; i < 8; ++i)
#pragma unroll
    for (int j = 0; j < 8; ++j) acc2[i][j] = 0.f;

#pragma unroll 2
  for (int kk = 0; kk < C4_; ++kk) {
    const float4 m0 = *(const float4*)(Mm + (size_t)kk * HD_ + ct * 8);
    const float4 m1 = *(const float4*)(Mm + (size_t)kk * HD_ + ct * 8 + 4);
    const float mv[8] = {m0.x, m0.y, m0.z, m0.w, m1.x, m1.y, m1.z, m1.w};
    float hv[8];
#pragma unroll
    for (int i = 0; i < 8; ++i) hv[i] = Hs[rt2 * 8 + i][kk];
#pragma unroll
    for (int i = 0; i < 8; ++i)
#pragma unroll
      for (int j = 0; j < 8; ++j) acc2[i][j] = fmaf(hv[i], mv[j], acc2[i][j]);
  }

  float dvv[8], v2v[8];
#pragma unroll
  for (int j = 0; j < 8; ++j) { dvv[j] = dv[ct * 8 + j]; v2v[j] = V2[ct * 8 + j]; }
  const float c2v = c2[0];
#pragma unroll
  for (int i = 0; i < 8; ++i) {
    float s = 0.f;
#pragma unroll
    for (int j = 0; j < 8; ++j) {
      float g = fmaxf(acc2[i][j] + dvv[j], 0.f);
      s = fmaf(g, v2v[j], s);
    }
#pragma unroll
    for (int off = 1; off < 32; off <<= 1) s += __shfl_xor(s, off);
    if (ct == 0) imp[(size_t)(row0 + rt2 * 8 + i)] = s + c2v;
  }
}

// ---------- E: per-b top-38 of imp -> swap_map ----------
__global__ __launch_bounds__(64) void k_top38(const float* __restrict__ imp,
                                              int* __restrict__ swap_map) {
  const int b = blockIdx.x;
  const int t = threadIdx.x;
  __shared__ float vals[N_];
  __shared__ int top[NSP_];
  for (int i = t; i < N_; i += 64) vals[i] = imp[(size_t)b * N_ + i];
  for (int i = t; i < N_ - 1; i += 64) swap_map[b * (N_ - 1) + i] = -1;
  __syncthreads();
  for (int it = 0; it < NSP_; ++it) {
    float v = -INFINITY; int idx = N_;
    for (int i = t; i < N_; i += 64) {
      float x = vals[i];
      if (x > v || (x == v && i < idx)) { v = x; idx = i; }
    }
    for (int off = 32; off > 0; off >>= 1) {
      float ov = __shfl_xor(v, off);
      int   oi = __shfl_xor(idx, off);
      if (ov > v || (ov == v && oi < idx)) { v = ov; idx = oi; }
    }
    if (t == 0) { top[it] = idx; vals[idx] = -INFINITY; }
    __syncthreads();
  }
  if (t == 0) {
    for (int it = 0; it < NSP_; ++it) {
      const int idx = top[it];
      const int adj = idx > 0 ? idx - 1 : 0;
      swap_map[b * (N_ - 1) + adj] = it;   // rank order, last wins (numpy semantics)
    }
  }
}

// ---------- F: out = 0.7*features + 0.3*swapped ----------
__global__ __launch_bounds__(192) void k_blend(const float* __restrict__ F,
                                               const float* __restrict__ cls_n,
                                               const int* __restrict__ swap_map,
                                               const int* __restrict__ swap_choice,
                                               const int* __restrict__ swap_idx,
                                               float* __restrict__ out) {
  const int token = blockIdx.x;
  const int b = token / N_;
  const int n = token - b * N_;
  const int t = threadIdx.x;
  const float4* fin = (const float4*)(F + (size_t)token * C_);
  float4 x = fin[t];
  float4 y = x;
  if (n > 0) {
    const int it = swap_map[b * (N_ - 1) + n - 1];
    if (it >= 0) {
      const int choice = swap_choice[b * NSP_ + it];
      const int sb = swap_idx[b * 2 + choice];
      y = ((const float4*)(cls_n + (size_t)sb * C_))[t];
    }
  }
  float4 o;
  o.x = 0.7f * x.x + 0.3f * y.x;
  o.y = 0.7f * x.y + 0.3f * y.y;
  o.z = 0.7f * x.z + 0.3f * y.z;
  o.w = 0.7f * x.w + 0.3f * y.w;
  ((float4*)(out + (size_t)token * C_))[t] = o;
}

extern "C" void kernel_launch(void* const* d_in, const int* in_sizes, int n_in,
                              void* d_out, int out_size, void* d_ws, size_t ws_size,
                              hipStream_t stream) {
  const float* F   = (const float*)d_in[0];
  const float* W1  = (const float*)d_in[1];
  const float* b1  = (const float*)d_in[2];
  const float* W2  = (const float*)d_in[3];
  const float* b2  = (const float*)d_in[4];
  const float* V1  = (const float*)d_in[5];
  const float* c1  = (const float*)d_in[6];
  const float* V2  = (const float*)d_in[7];
  const float* c2  = (const float*)d_in[8];
  const int* labels      = (const int*)d_in[9];
  const int* swap_choice = (const int*)d_in[10];
  float* out = (float*)d_out;

  char* ws = (char*)d_ws;
  size_t off = 0;
  auto alloc = [&](size_t bytes) -> void* {
    void* p = ws + off;
    off = (off + bytes + 255) & ~(size_t)255;
    return p;
  };
  float* cls_n   = (float*)alloc((size_t)B_ * C_ * 4);
  float* cls_nT  = (float*)alloc((size_t)C_ * B_ * 4);
  unsigned short* W1h = (unsigned short*)alloc((size_t)C_ * C4_ * 2);
  unsigned short* W1m = (unsigned short*)alloc((size_t)C_ * C4_ * 2);
  unsigned short* W1l = (unsigned short*)alloc((size_t)C_ * C4_ * 2);
  float* Mm      = (float*)alloc((size_t)C4_ * HD_ * 4);
  float* dv      = (float*)alloc((size_t)HD_ * 4);
  float* imp     = (float*)alloc((size_t)NTOK_ * 4);
  int*   swapIdx = (int*)alloc((size_t)B_ * 2 * 4);
  int*   swapMap = (int*)alloc((size_t)B_ * (N_ - 1) * 4);
  if (off > ws_size) return;

  k_clsnorm<<<B_, 256, 0, stream>>>(F, cls_n, cls_nT);
  k_sim_top4<<<B_, 256, 0, stream>>>(cls_nT, labels, swapIdx);
  k_w1frag<<<C_, C4_, 0, stream>>>(W1, W1h, W1m, W1l);
  k_M<<<C4_, HD_, 0, stream>>>(W2, V1, Mm);
  k_d<<<1, HD_, 0, stream>>>(b2, V1, c1, dv);
  k_fused2<<<NTOK_ / 64, 256, 0, stream>>>(F, W1h, W1m, W1l, b1, Mm, dv, V2, c2, imp);
  k_top38<<<B_, 64, 0, stream>>>(imp, swapMap);
  k_blend<<<NTOK_, 192, 0, stream>>>(F, cls_n, swapMap, swap_choice, swapIdx, out);
}

// Round 7
// 448.868 us; speedup vs baseline: 1.4855x; 1.1745x over previous
//
#include <hip/hip_runtime.h>
#include <math.h>

#define B_   256
#define N_   129
#define C_   768
#define C4_  192
#define HD_  256
#define NSP_ 38
#define NTOK_ (B_*N_)   // 33024

typedef __attribute__((ext_vector_type(8))) short bf16x8;
typedef __attribute__((ext_vector_type(4))) float f32x4;
typedef __attribute__((ext_vector_type(4))) unsigned short u16x4;

static __device__ __forceinline__ unsigned short f2bf(float x) {
  unsigned u = __float_as_uint(x);
  u += 0x7FFFu + ((u >> 16) & 1u);
  return (unsigned short)(u >> 16);
}
static __device__ __forceinline__ float bf2f(unsigned short h) {
  return __uint_as_float(((unsigned)h) << 16);
}
// 3-way RTN split (weights, one-off): residual ~2^-27 |x|
static __device__ __forceinline__ void split3(float x, unsigned short& h,
                                              unsigned short& m, unsigned short& l) {
  h = f2bf(x);
  float r1 = x - bf2f(h);
  m = f2bf(r1);
  float r2 = r1 - bf2f(m);
  l = f2bf(r2);
}

// ---------- A: cls_n = cls / max(||cls||, eps); also transposed copy ----------
__global__ __launch_bounds__(256) void k_clsnorm(const float* __restrict__ F,
                                                 float* __restrict__ cls_n,
                                                 float* __restrict__ cls_nT) {
  const int b = blockIdx.x;
  const int t = threadIdx.x;
  const float* row = F + (size_t)b * (N_ * C_);
  float s = 0.f;
  for (int k = t; k < C_; k += 256) { float v = row[k]; s += v * v; }
  for (int off = 32; off > 0; off >>= 1) s += __shfl_down(s, off);
  __shared__ float red[4];
  __shared__ float inv_s;
  if ((t & 63) == 0) red[t >> 6] = s;
  __syncthreads();
  if (t == 0) {
    float tot = red[0] + red[1] + red[2] + red[3];
    inv_s = 1.f / fmaxf(sqrtf(tot), 1e-12f);
  }
  __syncthreads();
  const float inv = inv_s;
  for (int k = t; k < C_; k += 256) {
    float v = row[k] * inv;
    cls_n[(size_t)b * C_ + k] = v;
    cls_nT[(size_t)k * B_ + b] = v;
  }
}

// ---------- B: sim, mask same-label, top-4, keep ranks 2,3 ----------
__global__ __launch_bounds__(256) void k_sim_top4(const float* __restrict__ cls_nT,
                                                  const int* __restrict__ labels,
                                                  int* __restrict__ swap_idx) {
  const int b = blockIdx.x;
  const int t = threadIdx.x;  // candidate j
  __shared__ float a[C_];
  for (int k = t; k < C_; k += 256) a[k] = cls_nT[(size_t)k * B_ + b];
  __syncthreads();
  const int lb = labels[b];
  float s;
  if (labels[t] == lb) {
    s = -INFINITY;
  } else {
    float acc = 0.f;
#pragma unroll 8
    for (int k = 0; k < C_; ++k) acc = fmaf(a[k], cls_nT[(size_t)k * B_ + t], acc);
    s = acc;
  }
  __shared__ float svals[B_];
  __shared__ float wv[4];
  __shared__ int   wi[4];
  __shared__ int   top4[4];
  svals[t] = s;
  for (int it = 0; it < 4; ++it) {
    __syncthreads();
    float v = svals[t]; int idx = t;
    for (int off = 32; off > 0; off >>= 1) {
      float ov = __shfl_down(v, off);
      int   oi = __shfl_down(idx, off);
      if (ov > v || (ov == v && oi < idx)) { v = ov; idx = oi; }
    }
    if ((t & 63) == 0) { wv[t >> 6] = v; wi[t >> 6] = idx; }
    __syncthreads();
    if (t == 0) {
      float bv = wv[0]; int bi = wi[0];
      for (int w = 1; w < 4; ++w)
        if (wv[w] > bv || (wv[w] == bv && wi[w] < bi)) { bv = wv[w]; bi = wi[w]; }
      top4[it] = bi;
      svals[bi] = -INFINITY;
    }
  }
  __syncthreads();
  if (t == 0) { swap_idx[b * 2 + 0] = top4[2]; swap_idx[b * 2 + 1] = top4[3]; }
}

// ---------- prep: W1 frag split (blocks 0..767) | M=W2@V1 (768..959) | dv (960) ----------
__global__ __launch_bounds__(256) void k_prep(const float* __restrict__ W1,
                                              const float* __restrict__ W2,
                                              const float* __restrict__ V1,
                                              const float* __restrict__ b2,
                                              const float* __restrict__ c1,
                                              unsigned short* __restrict__ W1h,
                                              unsigned short* __restrict__ W1m,
                                              unsigned short* __restrict__ W1l,
                                              float* __restrict__ Mm,
                                              float* __restrict__ dv) {
  const int bid = blockIdx.x;
  const int t = threadIdx.x;
  if (bid < 768) {                 // W1 fragment split, k=bid, n=t
    if (t < C4_) {
      const int k = bid, n = t;
      const float x = W1[(size_t)k * C4_ + n];
      const int ks = k >> 5, nt = n >> 4;
      const int ll = ((k >> 3) & 3) * 16 + (n & 15);
      const int jj = k & 7;
      const size_t flat = (((size_t)nt * 24 + ks) * 64 + ll) * 8 + jj;
      unsigned short h, m, l;
      split3(x, h, m, l);
      W1h[flat] = h; W1m[flat] = m; W1l[flat] = l;
    }
  } else if (bid < 960) {          // M row i
    const int i = bid - 768, j = t;
    const float* w2r = W2 + (size_t)i * C_;
    float acc = 0.f;
#pragma unroll 8
    for (int k = 0; k < C_; ++k) acc = fmaf(w2r[k], V1[(size_t)k * HD_ + j], acc);
    Mm[(size_t)i * HD_ + j] = acc;
  } else {                         // dv = b2@V1 + c1
    const int j = t;
    float acc = c1[j];
#pragma unroll 8
    for (int k = 0; k < C_; ++k) acc = fmaf(b2[k], V1[(size_t)k * HD_ + j], acc);
    dv[j] = acc;
  }
}

#define MFMA6(ACC, AH, AM, AL, BH, BM, BL)                                   \
  ACC = __builtin_amdgcn_mfma_f32_16x16x32_bf16(AH, BH, ACC, 0, 0, 0);       \
  ACC = __builtin_amdgcn_mfma_f32_16x16x32_bf16(AH, BM, ACC, 0, 0, 0);       \
  ACC = __builtin_amdgcn_mfma_f32_16x16x32_bf16(AM, BH, ACC, 0, 0, 0);       \
  ACC = __builtin_amdgcn_mfma_f32_16x16x32_bf16(AM, BM, ACC, 0, 0, 0);       \
  ACC = __builtin_amdgcn_mfma_f32_16x16x32_bf16(AH, BL, ACC, 0, 0, 0);       \
  ACC = __builtin_amdgcn_mfma_f32_16x16x32_bf16(AL, BH, ACC, 0, 0, 0);

// ---------- fused: stage1 split-bf16 MFMA (F@W1), stage2/3 fp32 VALU ----------
// 32-row tiles, 1032 blocks, dbuf A staging (1 barrier/iter), LDS 25.9 KB.
__global__ __launch_bounds__(256) void k_fused3(const float* __restrict__ F,
                                                const unsigned short* __restrict__ W1h,
                                                const unsigned short* __restrict__ W1m,
                                                const unsigned short* __restrict__ W1l,
                                                const float* __restrict__ b1,
                                                const float* __restrict__ Mm,
                                                const float* __restrict__ dv,
                                                const float* __restrict__ V2,
                                                const float* __restrict__ c2,
                                                float* __restrict__ imp) {
  __shared__ __align__(16) char smem[32 * 202 * 4];   // 25856 B
  unsigned short (*Ah)[32][40] = (unsigned short(*)[32][40])(smem);           // 5120 B
  unsigned short (*Am)[32][40] = (unsigned short(*)[32][40])(smem + 5120);    // 5120 B
  unsigned short (*Al)[32][40] = (unsigned short(*)[32][40])(smem + 10240);   // 5120 B
  float (*Hs)[202] = (float(*)[202])(smem);           // overlays A (sync'd)

  const int t = threadIdx.x;
  const int w = t >> 6;
  const int l = t & 63;
  const int l15 = l & 15, l4 = l >> 4;
  const int row0 = blockIdx.x * 32;

  f32x4 acc[2][3];
#pragma unroll
  for (int i = 0; i < 2; ++i)
#pragma unroll
    for (int j = 0; j < 3; ++j) acc[i][j] = (f32x4){0.f, 0.f, 0.f, 0.f};

  // staging map: thread -> (row sr, k-quad sk)
  const int sr = t >> 3;        // 0..31
  const int sk = (t & 7) * 4;   // 0..28
  const float* fptr = F + (size_t)(row0 + sr) * C_ + sk;

  float4 p = *(const float4*)(fptr);

  for (int ks = 0; ks < 24; ++ks) {
    const int buf = ks & 1;
    {  // split (h,m truncated — captured downstream; l RTN) and write to LDS
      float xs[4] = {p.x, p.y, p.z, p.w};
      u16x4 hv, mv, lv;
#pragma unroll
      for (int j = 0; j < 4; ++j) {
        const unsigned u = __float_as_uint(xs[j]);
        const float hf = __uint_as_float(u & 0xFFFF0000u);
        const float r1 = xs[j] - hf;
        const unsigned u1 = __float_as_uint(r1);
        const float mf = __uint_as_float(u1 & 0xFFFF0000u);
        const float r2 = r1 - mf;
        hv[j] = (unsigned short)(u >> 16);
        mv[j] = (unsigned short)(u1 >> 16);
        lv[j] = f2bf(r2);
      }
      *(u16x4*)&Ah[buf][sr][sk] = hv;
      *(u16x4*)&Am[buf][sr][sk] = mv;
      *(u16x4*)&Al[buf][sr][sk] = lv;
    }
    if (ks + 1 < 24) p = *(const float4*)(fptr + (ks + 1) * 32);
    __syncthreads();   // tile ready (dbuf: write(ks+1) won't touch buf until next iter)

    bf16x8 afh[2], afm[2], afl[2];
#pragma unroll
    for (int rt = 0; rt < 2; ++rt) {
      afh[rt] = *(const bf16x8*)&Ah[buf][16 * rt + l15][l4 * 8];
      afm[rt] = *(const bf16x8*)&Am[buf][16 * rt + l15][l4 * 8];
      afl[rt] = *(const bf16x8*)&Al[buf][16 * rt + l15][l4 * 8];
    }
#pragma unroll
    for (int ntl = 0; ntl < 3; ++ntl) {
      const int nt = 3 * w + ntl;
      const size_t boff = (((size_t)nt * 24 + ks) * 64 + l) * 8;
      const bf16x8 bh = *(const bf16x8*)(W1h + boff);
      const bf16x8 bm = *(const bf16x8*)(W1m + boff);
      const bf16x8 bl = *(const bf16x8*)(W1l + boff);
#pragma unroll
      for (int rt = 0; rt < 2; ++rt) {
        MFMA6(acc[rt][ntl], afh[rt], afm[rt], afl[rt], bh, bm, bl)
      }
    }
  }

  // epilogue stage1: H = relu(acc + b1) -> fp32 LDS (overlays dead A planes)
  float b1v[3];
#pragma unroll
  for (int ntl = 0; ntl < 3; ++ntl) b1v[ntl] = b1[16 * (3 * w + ntl) + l15];
  __syncthreads();   // all waves done reading A planes
#pragma unroll
  for (int rt = 0; rt < 2; ++rt)
#pragma unroll
    for (int ntl = 0; ntl < 3; ++ntl) {
      const int col = 16 * (3 * w + ntl) + l15;
#pragma unroll
      for (int r = 0; r < 4; ++r) {
        const int row = 16 * rt + l4 * 4 + r;
        Hs[row][col] = fmaxf(acc[rt][ntl][r] + b1v[ntl], 0.f);
      }
    }
  __syncthreads();

  // stage2: pre = H @ M in exact fp32 (r6-passing semantics), stage3 fused
  const int ct = t & 31;   // 32 col-threads * 8 cols = 256
  const int rt2 = t >> 5;  // 8 row-groups * 4 rows = 32
  float acc2[4][8];
#pragma unroll
  for (int i = 0; i < 4; ++i)
#pragma unroll
    for (int j = 0; j < 8; ++j) acc2[i][j] = 0.f;

#pragma unroll 2
  for (int kk = 0; kk < C4_; ++kk) {
    const float4 m0 = *(const float4*)(Mm + (size_t)kk * HD_ + ct * 8);
    const float4 m1 = *(const float4*)(Mm + (size_t)kk * HD_ + ct * 8 + 4);
    const float mv[8] = {m0.x, m0.y, m0.z, m0.w, m1.x, m1.y, m1.z, m1.w};
    float hv[4];
#pragma unroll
    for (int i = 0; i < 4; ++i) hv[i] = Hs[rt2 * 4 + i][kk];
#pragma unroll
    for (int i = 0; i < 4; ++i)
#pragma unroll
      for (int j = 0; j < 8; ++j) acc2[i][j] = fmaf(hv[i], mv[j], acc2[i][j]);
  }

  float dvv[8], v2v[8];
#pragma unroll
  for (int j = 0; j < 8; ++j) { dvv[j] = dv[ct * 8 + j]; v2v[j] = V2[ct * 8 + j]; }
  const float c2v = c2[0];
#pragma unroll
  for (int i = 0; i < 4; ++i) {
    float s = 0.f;
#pragma unroll
    for (int j = 0; j < 8; ++j) {
      float g = fmaxf(acc2[i][j] + dvv[j], 0.f);
      s = fmaf(g, v2v[j], s);
    }
#pragma unroll
    for (int off = 1; off < 32; off <<= 1) s += __shfl_xor(s, off);
    if (ct == 0) imp[(size_t)(row0 + rt2 * 4 + i)] = s + c2v;
  }
}

// ---------- E: per-b top-38 -> srcIdx[b][n-1] = source cls row (-1 = keep) ----------
__global__ __launch_bounds__(64) void k_top38(const float* __restrict__ imp,
                                              const int* __restrict__ swap_choice,
                                              const int* __restrict__ swap_idx,
                                              int* __restrict__ srcIdx) {
  const int b = blockIdx.x;
  const int t = threadIdx.x;
  __shared__ float vals[N_];
  __shared__ int top[NSP_];
  for (int i = t; i < N_; i += 64) vals[i] = imp[(size_t)b * N_ + i];
  for (int i = t; i < N_ - 1; i += 64) srcIdx[b * (N_ - 1) + i] = -1;
  __syncthreads();
  for (int it = 0; it < NSP_; ++it) {
    float v = -INFINITY; int idx = N_;
    for (int i = t; i < N_; i += 64) {
      float x = vals[i];
      if (x > v || (x == v && i < idx)) { v = x; idx = i; }
    }
    for (int off = 32; off > 0; off >>= 1) {
      float ov = __shfl_xor(v, off);
      int   oi = __shfl_xor(idx, off);
      if (ov > v || (ov == v && oi < idx)) { v = ov; idx = oi; }
    }
    if (t == 0) { top[it] = idx; vals[idx] = -INFINITY; }
    __syncthreads();
  }
  if (t == 0) {
    for (int it = 0; it < NSP_; ++it) {
      const int idx = top[it];
      const int adj = idx > 0 ? idx - 1 : 0;
      // rank order, last wins (numpy fancy-assign semantics)
      srcIdx[b * (N_ - 1) + adj] = swap_idx[b * 2 + swap_choice[b * NSP_ + it]];
    }
  }
}

// ---------- F: out = 0.7*features + 0.3*swapped, grid-stride float4 ----------
__global__ __launch_bounds__(256) void k_blend(const float* __restrict__ F,
                                               const float* __restrict__ cls_n,
                                               const int* __restrict__ srcIdx,
                                               float* __restrict__ out) {
  const int total = NTOK_ * (C_ / 4);   // 6,340,608 float4s
  const float4* fin = (const float4*)F;
  const float4* cl4 = (const float4*)cls_n;
  float4* o4 = (float4*)out;
  for (int idx = blockIdx.x * 256 + threadIdx.x; idx < total; idx += gridDim.x * 256) {
    const int token = idx / (C_ / 4);
    const int c4 = idx - token * (C_ / 4);
    const int b = token / N_;
    const int n = token - b * N_;
    float4 x = fin[idx];
    float4 y = x;
    if (n > 0) {
      const int s = srcIdx[b * (N_ - 1) + n - 1];
      if (s >= 0) y = cl4[s * (C_ / 4) + c4];
    }
    float4 o;
    o.x = 0.7f * x.x + 0.3f * y.x;
    o.y = 0.7f * x.y + 0.3f * y.y;
    o.z = 0.7f * x.z + 0.3f * y.z;
    o.w = 0.7f * x.w + 0.3f * y.w;
    o4[idx] = o;
  }
}

extern "C" void kernel_launch(void* const* d_in, const int* in_sizes, int n_in,
                              void* d_out, int out_size, void* d_ws, size_t ws_size,
                              hipStream_t stream) {
  const float* F   = (const float*)d_in[0];
  const float* W1  = (const float*)d_in[1];
  const float* b1  = (const float*)d_in[2];
  const float* W2  = (const float*)d_in[3];
  const float* b2  = (const float*)d_in[4];
  const float* V1  = (const float*)d_in[5];
  const float* c1  = (const float*)d_in[6];
  const float* V2  = (const float*)d_in[7];
  const float* c2  = (const float*)d_in[8];
  const int* labels      = (const int*)d_in[9];
  const int* swap_choice = (const int*)d_in[10];
  float* out = (float*)d_out;

  char* ws = (char*)d_ws;
  size_t off = 0;
  auto alloc = [&](size_t bytes) -> void* {
    void* p = ws + off;
    off = (off + bytes + 255) & ~(size_t)255;
    return p;
  };
  float* cls_n   = (float*)alloc((size_t)B_ * C_ * 4);
  float* cls_nT  = (float*)alloc((size_t)C_ * B_ * 4);
  unsigned short* W1h = (unsigned short*)alloc((size_t)C_ * C4_ * 2);
  unsigned short* W1m = (unsigned short*)alloc((size_t)C_ * C4_ * 2);
  unsigned short* W1l = (unsigned short*)alloc((size_t)C_ * C4_ * 2);
  float* Mm      = (float*)alloc((size_t)C4_ * HD_ * 4);
  float* dv      = (float*)alloc((size_t)HD_ * 4);
  float* imp     = (float*)alloc((size_t)NTOK_ * 4);
  int*   swapIdx = (int*)alloc((size_t)B_ * 2 * 4);
  int*   srcIdx  = (int*)alloc((size_t)B_ * (N_ - 1) * 4);
  if (off > ws_size) return;

  k_clsnorm<<<B_, 256, 0, stream>>>(F, cls_n, cls_nT);
  k_sim_top4<<<B_, 256, 0, stream>>>(cls_nT, labels, swapIdx);
  k_prep<<<961, 256, 0, stream>>>(W1, W2, V1, b2, c1, W1h, W1m, W1l, Mm, dv);
  k_fused3<<<NTOK_ / 32, 256, 0, stream>>>(F, W1h, W1m, W1l, b1, Mm, dv, V2, c2, imp);
  k_top38<<<B_, 64, 0, stream>>>(imp, swap_choice, swapIdx, srcIdx);
  k_blend<<<2048, 256, 0, stream>>>(F, cls_n, srcIdx, out);
}